// Round 16
// baseline (133.070 us; speedup 1.0000x reference)
//
#include <hip/hip_runtime.h>
#include <hip/hip_bf16.h>
#include <math.h>

#define NN 2048
#define NEG_SLOPE 0.2f

typedef __attribute__((ext_vector_type(8))) short bf16x8;
typedef __attribute__((ext_vector_type(4))) float f32x4;

static __device__ inline short f2bf(float x) {
  union { float f; unsigned u; } v;
  v.f = x;
  unsigned r = v.u + 0x7fffu + ((v.u >> 16) & 1u);  // RNE
  return (short)(r >> 16);
}

static __device__ inline float bf2f(short b) {
  union { unsigned u; float f; } v;
  v.u = ((unsigned)(unsigned short)b) << 16;
  return v.f;
}

// ---------------------------------------------------------------------------
// K1 k_pre: blocks 0-511: gemm1 (x @ W1, W1 staged per-block via LDS bf16-bit
// transpose) -> swizzled hTsw1 + ssrc/sdst partials. Blocks 512-1535: conv ->
// aggTb (bf16, 64x64 tile, LDS transpose) + fp32 stat partials; attn reads
// are NONTEMPORAL (201MB read-once stream; don't evict hot hTsw1/aggTb).
// 1536-1567: w2t. 1568: ce. gemm1 blocks first: their MFMA work overlaps the
// memory-bound conv blocks inside ONE dispatch (un-merging cost ~15us, R14).
// ---------------------------------------------------------------------------
__global__ __launch_bounds__(256) void k_pre(
    const float* __restrict__ attn, const float* __restrict__ conv_w,
    const float* __restrict__ conv_b, const float* __restrict__ x,
    const float* __restrict__ W1, const float* __restrict__ W2,
    const float* __restrict__ asrc1, const float* __restrict__ adst1,
    const float* __restrict__ ae1, const float* __restrict__ We1,
    const float* __restrict__ ae2, const float* __restrict__ We2,
    __hip_bfloat16* __restrict__ aggTb, float* __restrict__ ssum_part,
    float* __restrict__ scnt_part, __hip_bfloat16* __restrict__ hTsw1,
    float* __restrict__ sspart1, float* __restrict__ sdpart1,
    __hip_bfloat16* __restrict__ w2t, float* __restrict__ ce) {
  const int b = blockIdx.x;
  const int tid = threadIdx.x;
  __shared__ __align__(16) char smem[34816];
  if (b < 512) {
    // ---------------- gemm1 ----------------
    typedef short w1row[136];       // bf16 bit patterns, 272B rows (16B-align)
    w1row* w1s = (w1row*)smem;
    const int mb = b >> 2, cblk = b & 3;
    const int m0 = mb * 16;
    for (int e = tid; e < 128 * 32; e += 256) {
      int k = e >> 5, cq = (e & 31) * 4;
      f32x4 v = *(const f32x4*)(W1 + (size_t)k * 512 + cblk * 128 + cq);
#pragma unroll
      for (int j = 0; j < 4; ++j) w1s[cq + j][k] = f2bf(v[j]);
    }
    __syncthreads();
    const int wv = tid >> 6;
    const int lane = tid & 63, row = lane & 15, kg = lane >> 4;
    const int nb = cblk * 4 + wv;
    const int n0l = wv * 32;
    const float* axrow = x + (size_t)(m0 + row) * 128 + kg * 8;
    f32x4 acc[2];
#pragma unroll
    for (int f = 0; f < 2; ++f) acc[f] = (f32x4){0.f, 0.f, 0.f, 0.f};
#pragma unroll
    for (int ks = 0; ks < 4; ++ks) {
      f32x4 xa = *(const f32x4*)(axrow + ks * 32);
      f32x4 xb = *(const f32x4*)(axrow + ks * 32 + 4);
      bf16x8 Af = {f2bf(xa[0]), f2bf(xa[1]), f2bf(xa[2]), f2bf(xa[3]),
                   f2bf(xb[0]), f2bf(xb[1]), f2bf(xb[2]), f2bf(xb[3])};
#pragma unroll
      for (int f = 0; f < 2; ++f) {
        bf16x8 Bf = *(const bf16x8*)&w1s[n0l + f * 16 + row][kg * 8 + ks * 32];
        acc[f] =
            __builtin_amdgcn_mfma_f32_16x16x32_bf16(Af, Bf, acc[f], 0, 0, 0);
      }
    }
    const int h = nb >> 2;
    float as[2], ad[2];
#pragma unroll
    for (int f = 0; f < 2; ++f) {
      int ch = (n0l + f * 16 + row) & 127;
      as[f] = asrc1[h * 128 + ch];
      ad[f] = adst1[h * 128 + ch];
    }
    float ps[4] = {0.f, 0.f, 0.f, 0.f}, pd[4] = {0.f, 0.f, 0.f, 0.f};
#pragma unroll
    for (int f = 0; f < 2; ++f)
#pragma unroll
      for (int r = 0; r < 4; ++r) {
        ps[r] += acc[f][r] * as[f];
        pd[r] += acc[f][r] * ad[f];
      }
#pragma unroll
    for (int m = 1; m < 16; m <<= 1) {
#pragma unroll
      for (int r = 0; r < 4; ++r) {
        ps[r] += __shfl_xor(ps[r], m);
        pd[r] += __shfl_xor(pd[r], m);
      }
    }
    if (row == 0) {
#pragma unroll
      for (int r = 0; r < 4; ++r) {
        int node = m0 + kg * 4 + r;
        sspart1[nb * NN + node] = ps[r];
        sdpart1[nb * NN + node] = pd[r];
      }
    }
#pragma unroll
    for (int f = 0; f < 2; ++f) {
      const int cbi = nb * 2 + f;
      short4 ct;
      ct.x = f2bf(acc[f][0]); ct.y = f2bf(acc[f][1]);
      ct.z = f2bf(acc[f][2]); ct.w = f2bf(acc[f][3]);
      size_t a4 =
          (size_t)cbi * (NN * 16) +
          (size_t)(((m0 >> 3) + (kg >> 1)) * 128 + row * 8 + (kg & 1) * 4);
      *(short4*)((short*)hTsw1 + a4) = ct;
    }
  } else if (b < 1536) {
    // ---------------- conv -> aggTb (bf16) + fp32 stats ----------------
    typedef float trow[68];
    trow* tile = (trow*)smem;  // [64][68]
    const int b2 = b - 512;
    const int t0 = (b2 & 31) * 64;
    const int s0 = (b2 >> 5) * 64;
    const int sl = tid >> 4;
    const int t4 = (tid & 15) * 4;
    float w[12];
#pragma unroll
    for (int c = 0; c < 12; ++c) w[c] = conv_w[c];
    const float cb = conv_b[0];
    f32x4 acc[4];
#pragma unroll
    for (int k = 0; k < 4; ++k) acc[k] = (f32x4){cb, cb, cb, cb};
    for (int c = 0; c < 12; ++c) {
      const float* base =
          attn + (size_t)c * NN * NN + (size_t)(s0 + sl) * NN + t0 + t4;
#pragma unroll
      for (int k = 0; k < 4; ++k)
        acc[k] += w[c] * __builtin_nontemporal_load(
                             (const f32x4*)(base + (size_t)k * 16 * NN));
    }
#pragma unroll
    for (int k = 0; k < 4; ++k) *(f32x4*)&tile[sl + 16 * k][t4] = acc[k];
    __syncthreads();
    const int tl = tid >> 2;
    const int sq = (tid & 3) * 16;
    const int tglob = t0 + tl;
    float psum = 0.f, pcnt = 0.f;
    short bb[16];
#pragma unroll
    for (int g = 0; g < 4; ++g) {
      f32x4 v = {tile[sq + 4 * g][tl], tile[sq + 4 * g + 1][tl],
                 tile[sq + 4 * g + 2][tl], tile[sq + 4 * g + 3][tl]};
#pragma unroll
      for (int j = 0; j < 4; ++j) {
        bb[4 * g + j] = f2bf(v[j]);
        int sglob = s0 + sq + 4 * g + j;
        bool m = (v[j] > 0.f) && (sglob != tglob);
        psum += m ? v[j] : 0.f;
        pcnt += m ? 1.f : 0.f;
      }
    }
    {
      short* orow = (short*)aggTb + (size_t)tglob * NN + s0 + sq;
      bf16x8 lo = {bb[0], bb[1], bb[2], bb[3], bb[4], bb[5], bb[6], bb[7]};
      bf16x8 hi = {bb[8], bb[9], bb[10], bb[11], bb[12], bb[13], bb[14], bb[15]};
      *(bf16x8*)orow = lo;
      *(bf16x8*)(orow + 8) = hi;
    }
    psum += __shfl_down(psum, 1); psum += __shfl_down(psum, 2);
    pcnt += __shfl_down(pcnt, 1); pcnt += __shfl_down(pcnt, 2);
    if ((tid & 3) == 0) {
      ssum_part[(b2 >> 5) * NN + tglob] = psum;
      scnt_part[(b2 >> 5) * NN + tglob] = pcnt;
    }
  } else if (b < 1568) {
#pragma unroll
    for (int k = 0; k < 8; ++k) {
      int o = (b - 1536) * 2048 + k * 256 + tid;
      ((short*)w2t)[o] = f2bf(W2[(o & 511) * 128 + (o >> 9)]);
    }
  } else {
    const int lane = tid & 63;
    const int wv = tid >> 6;
    float q1 = ae1[wv * 128 + lane] * We1[wv * 128 + lane] +
               ae1[wv * 128 + 64 + lane] * We1[wv * 128 + 64 + lane];
    for (int off = 32; off; off >>= 1) q1 += __shfl_down(q1, off);
    if (lane == 0) ce[wv] = q1;
    float q2 = ae2[lane] * We2[lane] + ae2[64 + lane] * We2[64 + lane];
    for (int off = 32; off; off >>= 1) q2 += __shfl_down(q2, off);
    if (tid == 0) ce[4] = q2;
  }
}

// ---------------------------------------------------------------------------
// K2 attn1: 512 blocks = 128 t-tiles x 4 heads; 4 waves = 4 s-quarters.
// bf16 aggTb loads (1x 16B / 8 s); f2bf A-frag; cooperative mean_attr.
// ---------------------------------------------------------------------------
__global__ __launch_bounds__(256) void k_attn1(
    const __hip_bfloat16* __restrict__ aggTb,
    const __hip_bfloat16* __restrict__ hTsw1,
    const float* __restrict__ sspart1, const float* __restrict__ sdpart1,
    const float* __restrict__ ssum_part, const float* __restrict__ scnt_part,
    const float* __restrict__ ce_all, const float* __restrict__ b1,
    __hip_bfloat16* __restrict__ feat1b) {
  const int tid = threadIdx.x;
  const int t0 = (int)(blockIdx.x >> 2) * 16;
  const int h = (int)(blockIdx.x & 3u);
  __shared__ float ss_sh[2048];
  __shared__ float red[4][16][128];
  __shared__ float den_sh[4][16];
  __shared__ float mp_sh[2][16][16];
  __shared__ float ma_sh[16];
  for (int i = tid; i < 2048; i += 256)
    ss_sh[i] = sspart1[(4 * h + 0) * NN + i] + sspart1[(4 * h + 1) * NN + i] +
               sspart1[(4 * h + 2) * NN + i] + sspart1[(4 * h + 3) * NN + i];
  {
    int r = tid & 15, q2 = tid >> 4;  // q2: 0..15
    float s_ = ssum_part[(size_t)(2 * q2) * NN + t0 + r] +
               ssum_part[(size_t)(2 * q2 + 1) * NN + t0 + r];
    float c_ = scnt_part[(size_t)(2 * q2) * NN + t0 + r] +
               scnt_part[(size_t)(2 * q2 + 1) * NN + t0 + r];
    mp_sh[0][q2][r] = s_;
    mp_sh[1][q2][r] = c_;
  }
  __syncthreads();
  if (tid < 16) {
    float s_ = 0.f, c_ = 0.f;
#pragma unroll
    for (int q = 0; q < 16; ++q) { s_ += mp_sh[0][q][tid]; c_ += mp_sh[1][q][tid]; }
    ma_sh[tid] = s_ / fmaxf(c_, 1.f);
  }
  __syncthreads();
  const int lane = tid & 63, w = tid >> 6, row = lane & 15, kg = lane >> 4;
  const int sbeg = w * 512;
  const int tRow = t0 + row;
  const float ma_t = ma_sh[row];
  const float ce = ce_all[h];
  const float sd_t = sdpart1[(4 * h + 0) * NN + tRow] +
                     sdpart1[(4 * h + 1) * NN + tRow] +
                     sdpart1[(4 * h + 2) * NN + tRow] +
                     sdpart1[(4 * h + 3) * NN + tRow];
  const short* arowb = (const short*)aggTb + (size_t)tRow * NN;
  const float* ssh = ss_sh + sbeg;
  const __hip_bfloat16* bbase =
      hTsw1 + (size_t)(h * 8) * (NN * 16) + kg * 128 + row * 8;
  f32x4 acc[8];
#pragma unroll
  for (int f = 0; f < 8; ++f) acc[f] = (f32x4){0.f, 0.f, 0.f, 0.f};
  float dpart = 0.f;
  for (int s0 = sbeg; s0 < sbeg + 512; s0 += 32) {
    const int sk = s0 + kg * 8;
    bf16x8 araw = *(const bf16x8*)(arowb + sk);
    f32x4 sv0 = *(const f32x4*)(ssh + (sk - sbeg));
    f32x4 sv1 = *(const f32x4*)(ssh + (sk - sbeg) + 4);
    float sv[8] = {sv0[0], sv0[1], sv0[2], sv0[3],
                   sv1[0], sv1[1], sv1[2], sv1[3]};
    short pb[8];
#pragma unroll
    for (int j = 0; j < 8; ++j) {
      const int s = sk + j;
      const float a = bf2f(araw[j]);
      const bool diag = (s == tRow);
      const float ev = diag ? ma_t : a;
      const bool adj = diag || (a > 0.f);
      float l = sv[j] + sd_t + ev * ce;
      l = fmaxf(l, NEG_SLOPE * l);
      const float p = adj ? __expf(l) : 0.f;
      dpart += p;
      pb[j] = f2bf(p);
    }
    bf16x8 A = {pb[0], pb[1], pb[2], pb[3], pb[4], pb[5], pb[6], pb[7]};
    const __hip_bfloat16* bp = bbase + (size_t)s0 * 16;
#pragma unroll
    for (int f = 0; f < 8; ++f) {
      bf16x8 B = *(const bf16x8*)(bp + (size_t)f * (NN * 16));
      acc[f] = __builtin_amdgcn_mfma_f32_16x16x32_bf16(A, B, acc[f], 0, 0, 0);
    }
  }
  dpart += __shfl_xor(dpart, 16);
  dpart += __shfl_xor(dpart, 32);
  __syncthreads();
#pragma unroll
  for (int f = 0; f < 8; ++f)
#pragma unroll
    for (int r = 0; r < 4; ++r) red[w][kg * 4 + r][f * 16 + row] = acc[f][r];
  if (lane < 16) den_sh[w][lane] = dpart;
  __syncthreads();
#pragma unroll
  for (int i = 0; i < 8; ++i) {
    int idx = i * 256 + tid;
    int t = idx >> 7, c = idx & 127;
    float nsum = red[0][t][c] + red[1][t][c] + red[2][t][c] + red[3][t][c];
    float dsum = den_sh[0][t] + den_sh[1][t] + den_sh[2][t] + den_sh[3][t];
    float v = nsum / dsum + b1[h * 128 + c];
    feat1b[(size_t)(t0 + t) * 512 + h * 128 + c] =
        __float2bfloat16(v > 0.f ? v : 0.f);
  }
}

// ---------------------------------------------------------------------------
// K3 gemm2: h2 = feat1b @ W2 -> hTsw2; ssrc2/sdst2 via LDS cross-wave reduce.
// ---------------------------------------------------------------------------
__global__ __launch_bounds__(256) void k_gemm2(
    const __hip_bfloat16* __restrict__ feat1b,
    const __hip_bfloat16* __restrict__ w2t, const float* __restrict__ asrc2,
    const float* __restrict__ adst2, __hip_bfloat16* __restrict__ hTsw2,
    float* __restrict__ ssrc2, float* __restrict__ sdst2) {
  const int tid = threadIdx.x;
  const int wv = tid >> 6;
  const int w = (int)blockIdx.x * 4 + wv;  // 0..511
  const int lane = tid & 63, row = lane & 15, kg = lane >> 4;
  const int mb = w >> 2, nb = w & 3;
  const int m0 = mb * 16, n0 = nb * 32;
  __shared__ float sred[2][4][16];
  const __hip_bfloat16* arow = feat1b + (size_t)(m0 + row) * 512 + kg * 8;
  f32x4 acc[2];
#pragma unroll
  for (int f = 0; f < 2; ++f) acc[f] = (f32x4){0.f, 0.f, 0.f, 0.f};
#pragma unroll
  for (int ks = 0; ks < 16; ++ks) {
    bf16x8 Af = *(const bf16x8*)(arow + ks * 32);
#pragma unroll
    for (int f = 0; f < 2; ++f) {
      bf16x8 Bf = *(const bf16x8*)(w2t + (size_t)(n0 + f * 16 + row) * 512 +
                                   kg * 8 + ks * 32);
      acc[f] = __builtin_amdgcn_mfma_f32_16x16x32_bf16(Af, Bf, acc[f], 0, 0, 0);
    }
  }
  float as[2], ad[2];
#pragma unroll
  for (int f = 0; f < 2; ++f) {
    int ch = (n0 + f * 16 + row) & 127;
    as[f] = asrc2[ch];
    ad[f] = adst2[ch];
  }
  float ps[4] = {0.f, 0.f, 0.f, 0.f}, pd[4] = {0.f, 0.f, 0.f, 0.f};
#pragma unroll
  for (int f = 0; f < 2; ++f)
#pragma unroll
    for (int r = 0; r < 4; ++r) {
      ps[r] += acc[f][r] * as[f];
      pd[r] += acc[f][r] * ad[f];
    }
#pragma unroll
  for (int m = 1; m < 16; m <<= 1) {
#pragma unroll
    for (int r = 0; r < 4; ++r) {
      ps[r] += __shfl_xor(ps[r], m);
      pd[r] += __shfl_xor(pd[r], m);
    }
  }
  if (row == 0) {
#pragma unroll
    for (int r = 0; r < 4; ++r) {
      sred[0][wv][kg * 4 + r] = ps[r];
      sred[1][wv][kg * 4 + r] = pd[r];
    }
  }
  __syncthreads();
  if (tid < 16) {
    float s = sred[0][0][tid] + sred[0][1][tid] + sred[0][2][tid] +
              sred[0][3][tid];
    float d = sred[1][0][tid] + sred[1][1][tid] + sred[1][2][tid] +
              sred[1][3][tid];
    ssrc2[(int)blockIdx.x * 16 + tid] = s;
    sdst2[(int)blockIdx.x * 16 + tid] = d;
  }
#pragma unroll
  for (int f = 0; f < 2; ++f) {
    const int cbi = nb * 2 + f;
    short4 ct;
    ct.x = f2bf(acc[f][0]); ct.y = f2bf(acc[f][1]);
    ct.z = f2bf(acc[f][2]); ct.w = f2bf(acc[f][3]);
    size_t a4 = (size_t)cbi * (NN * 16) +
                (size_t)(((m0 >> 3) + (kg >> 1)) * 128 + row * 8 + (kg & 1) * 4);
    *(short4*)((short*)hTsw2 + a4) = ct;
  }
}

// ---------------------------------------------------------------------------
// K4 attn2 (1 head): 256 blocks = 128 t-tiles x 2 col-halves; 4 waves =
// s-quarters; bf16 aggTb; f2bf A-frag; cooperative mean; write feat2 direct.
// ---------------------------------------------------------------------------
__global__ __launch_bounds__(256) void k_attn2(
    const __hip_bfloat16* __restrict__ aggTb,
    const __hip_bfloat16* __restrict__ hTsw2,
    const float* __restrict__ ssrc2, const float* __restrict__ sdst2,
    const float* __restrict__ ssum_part, const float* __restrict__ scnt_part,
    const float* __restrict__ ce_all, const float* __restrict__ b2,
    float* __restrict__ feat2) {
  const int tid = threadIdx.x;
  const int t0 = (int)(blockIdx.x >> 1) * 16;
  const int chalf = (int)(blockIdx.x & 1u);
  __shared__ float ss_sh[2048];
  __shared__ float red[4][16][64];
  __shared__ float den_sh[4][16];
  __shared__ float mp_sh[2][16][16];
  __shared__ float ma_sh[16];
  for (int i = tid; i < 2048; i += 256) ss_sh[i] = ssrc2[i];
  {
    int r = tid & 15, q2 = tid >> 4;
    float s_ = ssum_part[(size_t)(2 * q2) * NN + t0 + r] +
               ssum_part[(size_t)(2 * q2 + 1) * NN + t0 + r];
    float c_ = scnt_part[(size_t)(2 * q2) * NN + t0 + r] +
               scnt_part[(size_t)(2 * q2 + 1) * NN + t0 + r];
    mp_sh[0][q2][r] = s_;
    mp_sh[1][q2][r] = c_;
  }
  __syncthreads();
  if (tid < 16) {
    float s_ = 0.f, c_ = 0.f;
#pragma unroll
    for (int q = 0; q < 16; ++q) { s_ += mp_sh[0][q][tid]; c_ += mp_sh[1][q][tid]; }
    ma_sh[tid] = s_ / fmaxf(c_, 1.f);
  }
  __syncthreads();
  const int lane = tid & 63, w = tid >> 6, row = lane & 15, kg = lane >> 4;
  const int sbeg = w * 512;
  const int tRow = t0 + row;
  const float ma_t = ma_sh[row];
  const float ce = ce_all[4];
  const float sd_t = sdst2[tRow];
  const short* arowb = (const short*)aggTb + (size_t)tRow * NN;
  const float* ssh = ss_sh + sbeg;
  const __hip_bfloat16* bbase =
      hTsw2 + (size_t)(chalf * 4) * (NN * 16) + kg * 128 + row * 8;
  f32x4 acc[4];
#pragma unroll
  for (int f = 0; f < 4; ++f) acc[f] = (f32x4){0.f, 0.f, 0.f, 0.f};
  float dpart = 0.f;
  for (int s0 = sbeg; s0 < sbeg + 512; s0 += 32) {
    const int sk = s0 + kg * 8;
    bf16x8 araw = *(const bf16x8*)(arowb + sk);
    f32x4 sv0 = *(const f32x4*)(ssh + (sk - sbeg));
    f32x4 sv1 = *(const f32x4*)(ssh + (sk - sbeg) + 4);
    float sv[8] = {sv0[0], sv0[1], sv0[2], sv0[3],
                   sv1[0], sv1[1], sv1[2], sv1[3]};
    short pb[8];
#pragma unroll
    for (int j = 0; j < 8; ++j) {
      const int s = sk + j;
      const float a = bf2f(araw[j]);
      const bool diag = (s == tRow);
      const float ev = diag ? ma_t : a;
      const bool adj = diag || (a > 0.f);
      float l = sv[j] + sd_t + ev * ce;
      l = fmaxf(l, NEG_SLOPE * l);
      const float p = adj ? __expf(l) : 0.f;
      dpart += p;
      pb[j] = f2bf(p);
    }
    bf16x8 A = {pb[0], pb[1], pb[2], pb[3], pb[4], pb[5], pb[6], pb[7]};
    const __hip_bfloat16* bp = bbase + (size_t)s0 * 16;
#pragma unroll
    for (int f = 0; f < 4; ++f) {
      bf16x8 B = *(const bf16x8*)(bp + (size_t)f * (NN * 16));
      acc[f] = __builtin_amdgcn_mfma_f32_16x16x32_bf16(A, B, acc[f], 0, 0, 0);
    }
  }
  dpart += __shfl_xor(dpart, 16);
  dpart += __shfl_xor(dpart, 32);
  __syncthreads();
#pragma unroll
  for (int f = 0; f < 4; ++f)
#pragma unroll
    for (int r = 0; r < 4; ++r) red[w][kg * 4 + r][f * 16 + row] = acc[f][r];
  if (lane < 16) den_sh[w][lane] = dpart;
  __syncthreads();
#pragma unroll
  for (int i = 0; i < 4; ++i) {
    int idx = i * 256 + tid;
    int t = idx >> 6, c = idx & 63;
    float nsum = red[0][t][c] + red[1][t][c] + red[2][t][c] + red[3][t][c];
    float dsum = den_sh[0][t] + den_sh[1][t] + den_sh[2][t] + den_sh[3][t];
    feat2[(size_t)(t0 + t) * 128 + chalf * 64 + c] =
        nsum / dsum + b2[chalf * 64 + c];
  }
}

// ---------------------------------------------------------------------------
// K5: segment mean pool + fc + log_softmax. 8 blocks x 256 threads.
// ---------------------------------------------------------------------------
__global__ __launch_bounds__(256) void k_poolhead(
    const float* __restrict__ feat, const int* __restrict__ bidx,
    const float* __restrict__ fcw, const float* __restrict__ fcb,
    float* __restrict__ out) {
  const int g = blockIdx.x;
  const int tid = threadIdx.x;
  __shared__ int lo[2];
  __shared__ float ps2[256];
  __shared__ float lsh[10];
  if (tid == 0) { lo[0] = NN; lo[1] = NN; }
  __syncthreads();
  for (int n = tid; n < NN; n += 256) {
    int b = bidx[n];
    int bprev = (n == 0) ? -1 : bidx[n - 1];
    if (b >= g && bprev < g) atomicMin(&lo[0], n);
    if (b >= g + 1 && bprev < g + 1) atomicMin(&lo[1], n);
  }
  __syncthreads();
  int s = lo[0], e = lo[1];
  const int c = tid & 127, half = tid >> 7;
  float sum = 0.f;
  for (int n = s + half; n < e; n += 2) sum += feat[(size_t)n * 128 + c];
  ps2[tid] = sum;
  __syncthreads();
  if (tid < 128) {
    float cntf = (float)((e - s) > 1 ? (e - s) : 1);
    ps2[tid] = (ps2[tid] + ps2[tid + 128]) / cntf;
  }
  __syncthreads();
  if (tid < 10) {
    float v = fcb[tid];
    for (int ch = 0; ch < 128; ++ch) v += ps2[ch] * fcw[ch * 10 + tid];
    lsh[tid] = v;
  }
  __syncthreads();
  if (tid < 10) {
    float m = -1e30f;
    for (int i = 0; i < 10; ++i) m = fmaxf(m, lsh[i]);
    float den = 0.f;
    for (int i = 0; i < 10; ++i) den += expf(lsh[i] - m);
    out[g * 10 + tid] = lsh[tid] - m - logf(den);
  }
}

extern "C" void kernel_launch(void* const* d_in, const int* in_sizes, int n_in,
                              void* d_out, int out_size, void* d_ws,
                              size_t ws_size, hipStream_t stream) {
  (void)in_sizes; (void)n_in; (void)out_size; (void)ws_size;
  const float* x      = (const float*)d_in[0];
  const float* attn   = (const float*)d_in[1];
  const int*   bidx   = (const int*)d_in[2];
  const float* conv_w = (const float*)d_in[3];
  const float* conv_b = (const float*)d_in[4];
  const float* W1     = (const float*)d_in[5];
  const float* asrc1  = (const float*)d_in[6];
  const float* adst1  = (const float*)d_in[7];
  const float* aedge1 = (const float*)d_in[8];
  const float* We1    = (const float*)d_in[9];
  const float* b1     = (const float*)d_in[10];
  const float* W2     = (const float*)d_in[11];
  const float* asrc2  = (const float*)d_in[12];
  const float* adst2  = (const float*)d_in[13];
  const float* aedge2 = (const float*)d_in[14];
  const float* We2    = (const float*)d_in[15];
  const float* b2     = (const float*)d_in[16];
  const float* fcw    = (const float*)d_in[17];
  const float* fcb    = (const float*)d_in[18];

  float* ws = (float*)d_ws;
  __hip_bfloat16* aggTb = (__hip_bfloat16*)ws;  // 4,194,304 el (2,097,152 fl)
  float* feat2     = ws + 2097152;         //   262,144
  float* ssum_part = feat2 + 262144;       //    65,536 (32 x 2048)
  float* scnt_part = ssum_part + 65536;    //    65,536
  float* sspart1   = scnt_part + 65536;    //    32,768 (16 x 2048)
  float* sdpart1   = sspart1 + 32768;      //    32,768
  float* ssrc2     = sdpart1 + 32768;      //     2,048
  float* sdst2     = ssrc2 + 2048;         //     2,048
  float* ce        = sdst2 + 2048;         //        64
  float* bf        = ce + 64;
  __hip_bfloat16* w2t    = (__hip_bfloat16*)bf;             //    65,536 el
  __hip_bfloat16* hTsw1  = (__hip_bfloat16*)(bf + 32768);   // 1,048,576 el
  __hip_bfloat16* hTsw2  = (__hip_bfloat16*)(bf + 557056);  //   262,144 el
  __hip_bfloat16* feat1b = (__hip_bfloat16*)(bf + 688128);  // 1,048,576 el

  k_pre<<<1569, 256, 0, stream>>>(attn, conv_w, conv_b, x, W1, W2, asrc1,
                                  adst1, aedge1, We1, aedge2, We2, aggTb,
                                  ssum_part, scnt_part, hTsw1, sspart1,
                                  sdpart1, w2t, ce);
  k_attn1<<<512, 256, 0, stream>>>(aggTb, hTsw1, sspart1, sdpart1, ssum_part,
                                   scnt_part, ce, b1, feat1b);
  k_gemm2<<<128, 256, 0, stream>>>(feat1b, w2t, asrc2, adst2, hTsw2, ssrc2,
                                   sdst2);
  k_attn2<<<256, 256, 0, stream>>>(aggTb, hTsw2, ssrc2, sdst2, ssum_part,
                                   scnt_part, ce, b2, feat2);
  k_poolhead<<<8, 256, 0, stream>>>(feat2, bidx, fcw, fcb, (float*)d_out);
}

// Round 17
// 123.850 us; speedup vs baseline: 1.0744x; 1.0744x over previous
//
#include <hip/hip_runtime.h>
#include <hip/hip_bf16.h>
#include <math.h>

#define NN 2048
#define NEG_SLOPE 0.2f

typedef __attribute__((ext_vector_type(8))) short bf16x8;
typedef __attribute__((ext_vector_type(4))) float f32x4;

static __device__ inline short f2bf(float x) {
  union { float f; unsigned u; } v;
  v.f = x;
  unsigned r = v.u + 0x7fffu + ((v.u >> 16) & 1u);  // RNE
  return (short)(r >> 16);
}

static __device__ inline float bf2f(short b) {
  union { unsigned u; float f; } v;
  v.u = ((unsigned)(unsigned short)b) << 16;
  return v.f;
}

// ---------------------------------------------------------------------------
// K1 k_pre: blocks 0-511: gemm1 (x @ W1, W1 staged per-block via LDS bf16-bit
// transpose) -> swizzled hTsw1 + ssrc/sdst partials. Blocks 512-1535: conv ->
// aggTb (bf16, 64x64 tile, LDS transpose) + fp32 stat partials (plain loads:
// nontemporal hint cost +8.5us, R16). 1536-1567: w2t. 1568: ce. gemm1 blocks
// first: their MFMA overlaps the memory-bound conv blocks in ONE dispatch.
// ---------------------------------------------------------------------------
__global__ __launch_bounds__(256) void k_pre(
    const float* __restrict__ attn, const float* __restrict__ conv_w,
    const float* __restrict__ conv_b, const float* __restrict__ x,
    const float* __restrict__ W1, const float* __restrict__ W2,
    const float* __restrict__ asrc1, const float* __restrict__ adst1,
    const float* __restrict__ ae1, const float* __restrict__ We1,
    const float* __restrict__ ae2, const float* __restrict__ We2,
    __hip_bfloat16* __restrict__ aggTb, float* __restrict__ ssum_part,
    float* __restrict__ scnt_part, __hip_bfloat16* __restrict__ hTsw1,
    float* __restrict__ sspart1, float* __restrict__ sdpart1,
    __hip_bfloat16* __restrict__ w2t, float* __restrict__ ce) {
  const int b = blockIdx.x;
  const int tid = threadIdx.x;
  __shared__ __align__(16) char smem[34816];
  if (b < 512) {
    // ---------------- gemm1 ----------------
    typedef short w1row[136];       // bf16 bit patterns, 272B rows (16B-align)
    w1row* w1s = (w1row*)smem;
    const int mb = b >> 2, cblk = b & 3;
    const int m0 = mb * 16;
    for (int e = tid; e < 128 * 32; e += 256) {
      int k = e >> 5, cq = (e & 31) * 4;
      f32x4 v = *(const f32x4*)(W1 + (size_t)k * 512 + cblk * 128 + cq);
#pragma unroll
      for (int j = 0; j < 4; ++j) w1s[cq + j][k] = f2bf(v[j]);
    }
    __syncthreads();
    const int wv = tid >> 6;
    const int lane = tid & 63, row = lane & 15, kg = lane >> 4;
    const int nb = cblk * 4 + wv;
    const int n0l = wv * 32;
    const float* axrow = x + (size_t)(m0 + row) * 128 + kg * 8;
    f32x4 acc[2];
#pragma unroll
    for (int f = 0; f < 2; ++f) acc[f] = (f32x4){0.f, 0.f, 0.f, 0.f};
#pragma unroll
    for (int ks = 0; ks < 4; ++ks) {
      f32x4 xa = *(const f32x4*)(axrow + ks * 32);
      f32x4 xb = *(const f32x4*)(axrow + ks * 32 + 4);
      bf16x8 Af = {f2bf(xa[0]), f2bf(xa[1]), f2bf(xa[2]), f2bf(xa[3]),
                   f2bf(xb[0]), f2bf(xb[1]), f2bf(xb[2]), f2bf(xb[3])};
#pragma unroll
      for (int f = 0; f < 2; ++f) {
        bf16x8 Bf = *(const bf16x8*)&w1s[n0l + f * 16 + row][kg * 8 + ks * 32];
        acc[f] =
            __builtin_amdgcn_mfma_f32_16x16x32_bf16(Af, Bf, acc[f], 0, 0, 0);
      }
    }
    const int h = nb >> 2;
    float as[2], ad[2];
#pragma unroll
    for (int f = 0; f < 2; ++f) {
      int ch = (n0l + f * 16 + row) & 127;
      as[f] = asrc1[h * 128 + ch];
      ad[f] = adst1[h * 128 + ch];
    }
    float ps[4] = {0.f, 0.f, 0.f, 0.f}, pd[4] = {0.f, 0.f, 0.f, 0.f};
#pragma unroll
    for (int f = 0; f < 2; ++f)
#pragma unroll
      for (int r = 0; r < 4; ++r) {
        ps[r] += acc[f][r] * as[f];
        pd[r] += acc[f][r] * ad[f];
      }
#pragma unroll
    for (int m = 1; m < 16; m <<= 1) {
#pragma unroll
      for (int r = 0; r < 4; ++r) {
        ps[r] += __shfl_xor(ps[r], m);
        pd[r] += __shfl_xor(pd[r], m);
      }
    }
    if (row == 0) {
#pragma unroll
      for (int r = 0; r < 4; ++r) {
        int node = m0 + kg * 4 + r;
        sspart1[nb * NN + node] = ps[r];
        sdpart1[nb * NN + node] = pd[r];
      }
    }
#pragma unroll
    for (int f = 0; f < 2; ++f) {
      const int cbi = nb * 2 + f;
      short4 ct;
      ct.x = f2bf(acc[f][0]); ct.y = f2bf(acc[f][1]);
      ct.z = f2bf(acc[f][2]); ct.w = f2bf(acc[f][3]);
      size_t a4 =
          (size_t)cbi * (NN * 16) +
          (size_t)(((m0 >> 3) + (kg >> 1)) * 128 + row * 8 + (kg & 1) * 4);
      *(short4*)((short*)hTsw1 + a4) = ct;
    }
  } else if (b < 1536) {
    // ---------------- conv -> aggTb (bf16) + fp32 stats ----------------
    typedef float trow[68];
    trow* tile = (trow*)smem;  // [64][68]
    const int b2 = b - 512;
    const int t0 = (b2 & 31) * 64;
    const int s0 = (b2 >> 5) * 64;
    const int sl = tid >> 4;
    const int t4 = (tid & 15) * 4;
    float w[12];
#pragma unroll
    for (int c = 0; c < 12; ++c) w[c] = conv_w[c];
    const float cb = conv_b[0];
    f32x4 acc[4];
#pragma unroll
    for (int k = 0; k < 4; ++k) acc[k] = (f32x4){cb, cb, cb, cb};
    for (int c = 0; c < 12; ++c) {
      const float* base =
          attn + (size_t)c * NN * NN + (size_t)(s0 + sl) * NN + t0 + t4;
#pragma unroll
      for (int k = 0; k < 4; ++k)
        acc[k] += w[c] * *(const f32x4*)(base + (size_t)k * 16 * NN);
    }
#pragma unroll
    for (int k = 0; k < 4; ++k) *(f32x4*)&tile[sl + 16 * k][t4] = acc[k];
    __syncthreads();
    const int tl = tid >> 2;
    const int sq = (tid & 3) * 16;
    const int tglob = t0 + tl;
    float psum = 0.f, pcnt = 0.f;
    short bb[16];
#pragma unroll
    for (int g = 0; g < 4; ++g) {
      f32x4 v = {tile[sq + 4 * g][tl], tile[sq + 4 * g + 1][tl],
                 tile[sq + 4 * g + 2][tl], tile[sq + 4 * g + 3][tl]};
#pragma unroll
      for (int j = 0; j < 4; ++j) {
        bb[4 * g + j] = f2bf(v[j]);
        int sglob = s0 + sq + 4 * g + j;
        bool m = (v[j] > 0.f) && (sglob != tglob);
        psum += m ? v[j] : 0.f;
        pcnt += m ? 1.f : 0.f;
      }
    }
    {
      short* orow = (short*)aggTb + (size_t)tglob * NN + s0 + sq;
      bf16x8 lo = {bb[0], bb[1], bb[2], bb[3], bb[4], bb[5], bb[6], bb[7]};
      bf16x8 hi = {bb[8], bb[9], bb[10], bb[11], bb[12], bb[13], bb[14], bb[15]};
      *(bf16x8*)orow = lo;
      *(bf16x8*)(orow + 8) = hi;
    }
    psum += __shfl_down(psum, 1); psum += __shfl_down(psum, 2);
    pcnt += __shfl_down(pcnt, 1); pcnt += __shfl_down(pcnt, 2);
    if ((tid & 3) == 0) {
      ssum_part[(b2 >> 5) * NN + tglob] = psum;
      scnt_part[(b2 >> 5) * NN + tglob] = pcnt;
    }
  } else if (b < 1568) {
#pragma unroll
    for (int k = 0; k < 8; ++k) {
      int o = (b - 1536) * 2048 + k * 256 + tid;
      ((short*)w2t)[o] = f2bf(W2[(o & 511) * 128 + (o >> 9)]);
    }
  } else {
    const int lane = tid & 63;
    const int wv = tid >> 6;
    float q1 = ae1[wv * 128 + lane] * We1[wv * 128 + lane] +
               ae1[wv * 128 + 64 + lane] * We1[wv * 128 + 64 + lane];
    for (int off = 32; off; off >>= 1) q1 += __shfl_down(q1, off);
    if (lane == 0) ce[wv] = q1;
    float q2 = ae2[lane] * We2[lane] + ae2[64 + lane] * We2[64 + lane];
    for (int off = 32; off; off >>= 1) q2 += __shfl_down(q2, off);
    if (tid == 0) ce[4] = q2;
  }
}

// ---------------------------------------------------------------------------
// K2 attn1: 512 blocks = 128 t-tiles x 4 heads; 4 waves = 4 s-quarters.
// bf16 aggTb loads (1x 16B / 8 s); f2bf A-frag; cooperative mean_attr.
// ---------------------------------------------------------------------------
__global__ __launch_bounds__(256) void k_attn1(
    const __hip_bfloat16* __restrict__ aggTb,
    const __hip_bfloat16* __restrict__ hTsw1,
    const float* __restrict__ sspart1, const float* __restrict__ sdpart1,
    const float* __restrict__ ssum_part, const float* __restrict__ scnt_part,
    const float* __restrict__ ce_all, const float* __restrict__ b1,
    __hip_bfloat16* __restrict__ feat1b) {
  const int tid = threadIdx.x;
  const int t0 = (int)(blockIdx.x >> 2) * 16;
  const int h = (int)(blockIdx.x & 3u);
  __shared__ float ss_sh[2048];
  __shared__ float red[4][16][128];
  __shared__ float den_sh[4][16];
  __shared__ float mp_sh[2][16][16];
  __shared__ float ma_sh[16];
  for (int i = tid; i < 2048; i += 256)
    ss_sh[i] = sspart1[(4 * h + 0) * NN + i] + sspart1[(4 * h + 1) * NN + i] +
               sspart1[(4 * h + 2) * NN + i] + sspart1[(4 * h + 3) * NN + i];
  {
    int r = tid & 15, q2 = tid >> 4;  // q2: 0..15
    float s_ = ssum_part[(size_t)(2 * q2) * NN + t0 + r] +
               ssum_part[(size_t)(2 * q2 + 1) * NN + t0 + r];
    float c_ = scnt_part[(size_t)(2 * q2) * NN + t0 + r] +
               scnt_part[(size_t)(2 * q2 + 1) * NN + t0 + r];
    mp_sh[0][q2][r] = s_;
    mp_sh[1][q2][r] = c_;
  }
  __syncthreads();
  if (tid < 16) {
    float s_ = 0.f, c_ = 0.f;
#pragma unroll
    for (int q = 0; q < 16; ++q) { s_ += mp_sh[0][q][tid]; c_ += mp_sh[1][q][tid]; }
    ma_sh[tid] = s_ / fmaxf(c_, 1.f);
  }
  __syncthreads();
  const int lane = tid & 63, w = tid >> 6, row = lane & 15, kg = lane >> 4;
  const int sbeg = w * 512;
  const int tRow = t0 + row;
  const float ma_t = ma_sh[row];
  const float ce = ce_all[h];
  const float sd_t = sdpart1[(4 * h + 0) * NN + tRow] +
                     sdpart1[(4 * h + 1) * NN + tRow] +
                     sdpart1[(4 * h + 2) * NN + tRow] +
                     sdpart1[(4 * h + 3) * NN + tRow];
  const short* arowb = (const short*)aggTb + (size_t)tRow * NN;
  const float* ssh = ss_sh + sbeg;
  const __hip_bfloat16* bbase =
      hTsw1 + (size_t)(h * 8) * (NN * 16) + kg * 128 + row * 8;
  f32x4 acc[8];
#pragma unroll
  for (int f = 0; f < 8; ++f) acc[f] = (f32x4){0.f, 0.f, 0.f, 0.f};
  float dpart = 0.f;
  for (int s0 = sbeg; s0 < sbeg + 512; s0 += 32) {
    const int sk = s0 + kg * 8;
    bf16x8 araw = *(const bf16x8*)(arowb + sk);
    f32x4 sv0 = *(const f32x4*)(ssh + (sk - sbeg));
    f32x4 sv1 = *(const f32x4*)(ssh + (sk - sbeg) + 4);
    float sv[8] = {sv0[0], sv0[1], sv0[2], sv0[3],
                   sv1[0], sv1[1], sv1[2], sv1[3]};
    short pb[8];
#pragma unroll
    for (int j = 0; j < 8; ++j) {
      const int s = sk + j;
      const float a = bf2f(araw[j]);
      const bool diag = (s == tRow);
      const float ev = diag ? ma_t : a;
      const bool adj = diag || (a > 0.f);
      float l = sv[j] + sd_t + ev * ce;
      l = fmaxf(l, NEG_SLOPE * l);
      const float p = adj ? __expf(l) : 0.f;
      dpart += p;
      pb[j] = f2bf(p);
    }
    bf16x8 A = {pb[0], pb[1], pb[2], pb[3], pb[4], pb[5], pb[6], pb[7]};
    const __hip_bfloat16* bp = bbase + (size_t)s0 * 16;
#pragma unroll
    for (int f = 0; f < 8; ++f) {
      bf16x8 B = *(const bf16x8*)(bp + (size_t)f * (NN * 16));
      acc[f] = __builtin_amdgcn_mfma_f32_16x16x32_bf16(A, B, acc[f], 0, 0, 0);
    }
  }
  dpart += __shfl_xor(dpart, 16);
  dpart += __shfl_xor(dpart, 32);
  __syncthreads();
#pragma unroll
  for (int f = 0; f < 8; ++f)
#pragma unroll
    for (int r = 0; r < 4; ++r) red[w][kg * 4 + r][f * 16 + row] = acc[f][r];
  if (lane < 16) den_sh[w][lane] = dpart;
  __syncthreads();
#pragma unroll
  for (int i = 0; i < 8; ++i) {
    int idx = i * 256 + tid;
    int t = idx >> 7, c = idx & 127;
    float nsum = red[0][t][c] + red[1][t][c] + red[2][t][c] + red[3][t][c];
    float dsum = den_sh[0][t] + den_sh[1][t] + den_sh[2][t] + den_sh[3][t];
    float v = nsum / dsum + b1[h * 128 + c];
    feat1b[(size_t)(t0 + t) * 512 + h * 128 + c] =
        __float2bfloat16(v > 0.f ? v : 0.f);
  }
}

// ---------------------------------------------------------------------------
// K3 gemm2: h2 = feat1b @ W2 -> hTsw2; ssrc2/sdst2 via LDS cross-wave reduce.
// ---------------------------------------------------------------------------
__global__ __launch_bounds__(256) void k_gemm2(
    const __hip_bfloat16* __restrict__ feat1b,
    const __hip_bfloat16* __restrict__ w2t, const float* __restrict__ asrc2,
    const float* __restrict__ adst2, __hip_bfloat16* __restrict__ hTsw2,
    float* __restrict__ ssrc2, float* __restrict__ sdst2) {
  const int tid = threadIdx.x;
  const int wv = tid >> 6;
  const int w = (int)blockIdx.x * 4 + wv;  // 0..511
  const int lane = tid & 63, row = lane & 15, kg = lane >> 4;
  const int mb = w >> 2, nb = w & 3;
  const int m0 = mb * 16, n0 = nb * 32;
  __shared__ float sred[2][4][16];
  const __hip_bfloat16* arow = feat1b + (size_t)(m0 + row) * 512 + kg * 8;
  f32x4 acc[2];
#pragma unroll
  for (int f = 0; f < 2; ++f) acc[f] = (f32x4){0.f, 0.f, 0.f, 0.f};
#pragma unroll
  for (int ks = 0; ks < 16; ++ks) {
    bf16x8 Af = *(const bf16x8*)(arow + ks * 32);
#pragma unroll
    for (int f = 0; f < 2; ++f) {
      bf16x8 Bf = *(const bf16x8*)(w2t + (size_t)(n0 + f * 16 + row) * 512 +
                                   kg * 8 + ks * 32);
      acc[f] = __builtin_amdgcn_mfma_f32_16x16x32_bf16(Af, Bf, acc[f], 0, 0, 0);
    }
  }
  float as[2], ad[2];
#pragma unroll
  for (int f = 0; f < 2; ++f) {
    int ch = (n0 + f * 16 + row) & 127;
    as[f] = asrc2[ch];
    ad[f] = adst2[ch];
  }
  float ps[4] = {0.f, 0.f, 0.f, 0.f}, pd[4] = {0.f, 0.f, 0.f, 0.f};
#pragma unroll
  for (int f = 0; f < 2; ++f)
#pragma unroll
    for (int r = 0; r < 4; ++r) {
      ps[r] += acc[f][r] * as[f];
      pd[r] += acc[f][r] * ad[f];
    }
#pragma unroll
  for (int m = 1; m < 16; m <<= 1) {
#pragma unroll
    for (int r = 0; r < 4; ++r) {
      ps[r] += __shfl_xor(ps[r], m);
      pd[r] += __shfl_xor(pd[r], m);
    }
  }
  if (row == 0) {
#pragma unroll
    for (int r = 0; r < 4; ++r) {
      sred[0][wv][kg * 4 + r] = ps[r];
      sred[1][wv][kg * 4 + r] = pd[r];
    }
  }
  __syncthreads();
  if (tid < 16) {
    float s = sred[0][0][tid] + sred[0][1][tid] + sred[0][2][tid] +
              sred[0][3][tid];
    float d = sred[1][0][tid] + sred[1][1][tid] + sred[1][2][tid] +
              sred[1][3][tid];
    ssrc2[(int)blockIdx.x * 16 + tid] = s;
    sdst2[(int)blockIdx.x * 16 + tid] = d;
  }
#pragma unroll
  for (int f = 0; f < 2; ++f) {
    const int cbi = nb * 2 + f;
    short4 ct;
    ct.x = f2bf(acc[f][0]); ct.y = f2bf(acc[f][1]);
    ct.z = f2bf(acc[f][2]); ct.w = f2bf(acc[f][3]);
    size_t a4 = (size_t)cbi * (NN * 16) +
                (size_t)(((m0 >> 3) + (kg >> 1)) * 128 + row * 8 + (kg & 1) * 4);
    *(short4*)((short*)hTsw2 + a4) = ct;
  }
}

// ---------------------------------------------------------------------------
// K4 attn2 (1 head): 256 blocks = 128 t-tiles x 2 col-halves; 4 waves =
// s-quarters; bf16 aggTb; f2bf A-frag; cooperative mean; write feat2 direct.
// ---------------------------------------------------------------------------
__global__ __launch_bounds__(256) void k_attn2(
    const __hip_bfloat16* __restrict__ aggTb,
    const __hip_bfloat16* __restrict__ hTsw2,
    const float* __restrict__ ssrc2, const float* __restrict__ sdst2,
    const float* __restrict__ ssum_part, const float* __restrict__ scnt_part,
    const float* __restrict__ ce_all, const float* __restrict__ b2,
    float* __restrict__ feat2) {
  const int tid = threadIdx.x;
  const int t0 = (int)(blockIdx.x >> 1) * 16;
  const int chalf = (int)(blockIdx.x & 1u);
  __shared__ float ss_sh[2048];
  __shared__ float red[4][16][64];
  __shared__ float den_sh[4][16];
  __shared__ float mp_sh[2][16][16];
  __shared__ float ma_sh[16];
  for (int i = tid; i < 2048; i += 256) ss_sh[i] = ssrc2[i];
  {
    int r = tid & 15, q2 = tid >> 4;
    float s_ = ssum_part[(size_t)(2 * q2) * NN + t0 + r] +
               ssum_part[(size_t)(2 * q2 + 1) * NN + t0 + r];
    float c_ = scnt_part[(size_t)(2 * q2) * NN + t0 + r] +
               scnt_part[(size_t)(2 * q2 + 1) * NN + t0 + r];
    mp_sh[0][q2][r] = s_;
    mp_sh[1][q2][r] = c_;
  }
  __syncthreads();
  if (tid < 16) {
    float s_ = 0.f, c_ = 0.f;
#pragma unroll
    for (int q = 0; q < 16; ++q) { s_ += mp_sh[0][q][tid]; c_ += mp_sh[1][q][tid]; }
    ma_sh[tid] = s_ / fmaxf(c_, 1.f);
  }
  __syncthreads();
  const int lane = tid & 63, w = tid >> 6, row = lane & 15, kg = lane >> 4;
  const int sbeg = w * 512;
  const int tRow = t0 + row;
  const float ma_t = ma_sh[row];
  const float ce = ce_all[4];
  const float sd_t = sdst2[tRow];
  const short* arowb = (const short*)aggTb + (size_t)tRow * NN;
  const float* ssh = ss_sh + sbeg;
  const __hip_bfloat16* bbase =
      hTsw2 + (size_t)(chalf * 4) * (NN * 16) + kg * 128 + row * 8;
  f32x4 acc[4];
#pragma unroll
  for (int f = 0; f < 4; ++f) acc[f] = (f32x4){0.f, 0.f, 0.f, 0.f};
  float dpart = 0.f;
  for (int s0 = sbeg; s0 < sbeg + 512; s0 += 32) {
    const int sk = s0 + kg * 8;
    bf16x8 araw = *(const bf16x8*)(arowb + sk);
    f32x4 sv0 = *(const f32x4*)(ssh + (sk - sbeg));
    f32x4 sv1 = *(const f32x4*)(ssh + (sk - sbeg) + 4);
    float sv[8] = {sv0[0], sv0[1], sv0[2], sv0[3],
                   sv1[0], sv1[1], sv1[2], sv1[3]};
    short pb[8];
#pragma unroll
    for (int j = 0; j < 8; ++j) {
      const int s = sk + j;
      const float a = bf2f(araw[j]);
      const bool diag = (s == tRow);
      const float ev = diag ? ma_t : a;
      const bool adj = diag || (a > 0.f);
      float l = sv[j] + sd_t + ev * ce;
      l = fmaxf(l, NEG_SLOPE * l);
      const float p = adj ? __expf(l) : 0.f;
      dpart += p;
      pb[j] = f2bf(p);
    }
    bf16x8 A = {pb[0], pb[1], pb[2], pb[3], pb[4], pb[5], pb[6], pb[7]};
    const __hip_bfloat16* bp = bbase + (size_t)s0 * 16;
#pragma unroll
    for (int f = 0; f < 4; ++f) {
      bf16x8 B = *(const bf16x8*)(bp + (size_t)f * (NN * 16));
      acc[f] = __builtin_amdgcn_mfma_f32_16x16x32_bf16(A, B, acc[f], 0, 0, 0);
    }
  }
  dpart += __shfl_xor(dpart, 16);
  dpart += __shfl_xor(dpart, 32);
  __syncthreads();
#pragma unroll
  for (int f = 0; f < 4; ++f)
#pragma unroll
    for (int r = 0; r < 4; ++r) red[w][kg * 4 + r][f * 16 + row] = acc[f][r];
  if (lane < 16) den_sh[w][lane] = dpart;
  __syncthreads();
#pragma unroll
  for (int i = 0; i < 4; ++i) {
    int idx = i * 256 + tid;
    int t = idx >> 6, c = idx & 63;
    float nsum = red[0][t][c] + red[1][t][c] + red[2][t][c] + red[3][t][c];
    float dsum = den_sh[0][t] + den_sh[1][t] + den_sh[2][t] + den_sh[3][t];
    feat2[(size_t)(t0 + t) * 128 + chalf * 64 + c] =
        nsum / dsum + b2[chalf * 64 + c];
  }
}

// ---------------------------------------------------------------------------
// K5: segment mean pool + fc + log_softmax. 8 blocks x 256 threads.
// ---------------------------------------------------------------------------
__global__ __launch_bounds__(256) void k_poolhead(
    const float* __restrict__ feat, const int* __restrict__ bidx,
    const float* __restrict__ fcw, const float* __restrict__ fcb,
    float* __restrict__ out) {
  const int g = blockIdx.x;
  const int tid = threadIdx.x;
  __shared__ int lo[2];
  __shared__ float ps2[256];
  __shared__ float lsh[10];
  if (tid == 0) { lo[0] = NN; lo[1] = NN; }
  __syncthreads();
  for (int n = tid; n < NN; n += 256) {
    int b = bidx[n];
    int bprev = (n == 0) ? -1 : bidx[n - 1];
    if (b >= g && bprev < g) atomicMin(&lo[0], n);
    if (b >= g + 1 && bprev < g + 1) atomicMin(&lo[1], n);
  }
  __syncthreads();
  int s = lo[0], e = lo[1];
  const int c = tid & 127, half = tid >> 7;
  float sum = 0.f;
  for (int n = s + half; n < e; n += 2) sum += feat[(size_t)n * 128 + c];
  ps2[tid] = sum;
  __syncthreads();
  if (tid < 128) {
    float cntf = (float)((e - s) > 1 ? (e - s) : 1);
    ps2[tid] = (ps2[tid] + ps2[tid + 128]) / cntf;
  }
  __syncthreads();
  if (tid < 10) {
    float v = fcb[tid];
    for (int ch = 0; ch < 128; ++ch) v += ps2[ch] * fcw[ch * 10 + tid];
    lsh[tid] = v;
  }
  __syncthreads();
  if (tid < 10) {
    float m = -1e30f;
    for (int i = 0; i < 10; ++i) m = fmaxf(m, lsh[i]);
    float den = 0.f;
    for (int i = 0; i < 10; ++i) den += expf(lsh[i] - m);
    out[g * 10 + tid] = lsh[tid] - m - logf(den);
  }
}

extern "C" void kernel_launch(void* const* d_in, const int* in_sizes, int n_in,
                              void* d_out, int out_size, void* d_ws,
                              size_t ws_size, hipStream_t stream) {
  (void)in_sizes; (void)n_in; (void)out_size; (void)ws_size;
  const float* x      = (const float*)d_in[0];
  const float* attn   = (const float*)d_in[1];
  const int*   bidx   = (const int*)d_in[2];
  const float* conv_w = (const float*)d_in[3];
  const float* conv_b = (const float*)d_in[4];
  const float* W1     = (const float*)d_in[5];
  const float* asrc1  = (const float*)d_in[6];
  const float* adst1  = (const float*)d_in[7];
  const float* aedge1 = (const float*)d_in[8];
  const float* We1    = (const float*)d_in[9];
  const float* b1     = (const float*)d_in[10];
  const float* W2     = (const float*)d_in[11];
  const float* asrc2  = (const float*)d_in[12];
  const float* adst2  = (const float*)d_in[13];
  const float* aedge2 = (const float*)d_in[14];
  const float* We2    = (const float*)d_in[15];
  const float* b2     = (const float*)d_in[16];
  const float* fcw    = (const float*)d_in[17];
  const float* fcb    = (const float*)d_in[18];

  float* ws = (float*)d_ws;
  __hip_bfloat16* aggTb = (__hip_bfloat16*)ws;  // 4,194,304 el (2,097,152 fl)
  float* feat2     = ws + 2097152;         //   262,144
  float* ssum_part = feat2 + 262144;       //    65,536 (32 x 2048)
  float* scnt_part = ssum_part + 65536;    //    65,536
  float* sspart1   = scnt_part + 65536;    //    32,768 (16 x 2048)
  float* sdpart1   = sspart1 + 32768;      //    32,768
  float* ssrc2     = sdpart1 + 32768;      //     2,048
  float* sdst2     = ssrc2 + 2048;         //     2,048
  float* ce        = sdst2 + 2048;         //        64
  float* bf        = ce + 64;
  __hip_bfloat16* w2t    = (__hip_bfloat16*)bf;             //    65,536 el
  __hip_bfloat16* hTsw1  = (__hip_bfloat16*)(bf + 32768);   // 1,048,576 el
  __hip_bfloat16* hTsw2  = (__hip_bfloat16*)(bf + 557056);  //   262,144 el
  __hip_bfloat16* feat1b = (__hip_bfloat16*)(bf + 688128);  // 1,048,576 el

  k_pre<<<1569, 256, 0, stream>>>(attn, conv_w, conv_b, x, W1, W2, asrc1,
                                  adst1, aedge1, We1, aedge2, We2, aggTb,
                                  ssum_part, scnt_part, hTsw1, sspart1,
                                  sdpart1, w2t, ce);
  k_attn1<<<512, 256, 0, stream>>>(aggTb, hTsw1, sspart1, sdpart1, ssum_part,
                                   scnt_part, ce, b1, feat1b);
  k_gemm2<<<128, 256, 0, stream>>>(feat1b, w2t, asrc2, adst2, hTsw2, ssrc2,
                                   sdst2);
  k_attn2<<<256, 256, 0, stream>>>(aggTb, hTsw2, ssrc2, sdst2, ssum_part,
                                   scnt_part, ce, b2, feat2);
  k_poolhead<<<8, 256, 0, stream>>>(feat2, bidx, fcw, fcb, (float*)d_out);
}